// Round 1
// baseline (778.746 us; speedup 1.0000x reference)
//
#include <hip/hip_runtime.h>
#include <hip/hip_bf16.h>
#include <cstdint>

typedef __attribute__((ext_vector_type(8))) __bf16 bf16x8;
typedef __attribute__((ext_vector_type(8))) unsigned short u16x8;
typedef __attribute__((ext_vector_type(4))) float f32x4;

#define QKSTRIDE 640
#define QKROW 1280
#define VTPAD 528

static __device__ __forceinline__ unsigned short f2bf(float f) {
  __hip_bfloat16 h = __float2bfloat16(f);
  return *reinterpret_cast<unsigned short*>(&h);
}

static __device__ __forceinline__ void gload_lds16(const void* g, void* lds) {
  __builtin_amdgcn_global_load_lds(
      (const __attribute__((address_space(1))) unsigned int*)g,
      (__attribute__((address_space(3))) unsigned int*)lds, 16, 0, 0);
}

// ---------------- prep: head dims, loss, column map ----------------
__global__ void prep_kernel(const float* __restrict__ logits, int* __restrict__ hdr,
                            int* __restrict__ cmap, float* __restrict__ loss_out) {
  if (threadIdx.x != 0 || blockIdx.x != 0) return;
  float l[6]; float mx = -1e30f;
  for (int i = 0; i < 6; ++i) { l[i] = logits[i]; mx = fmaxf(mx, l[i]); }
  float e[6]; float s = 0.f;
  for (int i = 0; i < 6; ++i) { e[i] = expf(l[i] - mx); s += e[i]; }
  float hdf[6]; float sumh = 0.f;
  for (int i = 0; i < 6; ++i) { hdf[i] = 8.0f + (e[i] / s) * 464.0f; sumh += hdf[i]; }
  int hdi[6]; float res[6]; int isum = 0;
  for (int i = 0; i < 6; ++i) {
    float fl = floorf(hdf[i]);
    hdi[i] = (int)fl; res[i] = hdf[i] - fl; isum += hdi[i];
  }
  int diff = 512 - isum;
  bool used[6] = {false, false, false, false, false, false};
  if (diff > 0) {
    for (int t = 0; t < diff; ++t) {
      int best = -1; float bv = -1e30f;
      for (int i = 0; i < 6; ++i) if (!used[i] && res[i] > bv) { bv = res[i]; best = i; }
      used[best] = true; hdi[best] += 1;
    }
  } else if (diff < 0) {
    for (int t = 0; t < -diff; ++t) {
      int best = -1; float bv = 1e30f;
      for (int i = 0; i < 6; ++i) if (!used[i] && res[i] < bv) { bv = res[i]; best = i; }
      used[best] = true; hdi[best] -= 1;
    }
  }
  int starts[6], astarts[6];
  { int st = 0, ast = 0;
    for (int i = 0; i < 6; ++i) {
      starts[i] = st; astarts[i] = ast;
      hdr[i] = hdi[i]; hdr[8 + i] = st; hdr[16 + i] = ast;
      st += hdi[i]; ast += (hdi[i] + 7) & ~7;
    } }
  for (int col = 0; col < 512; ++col) {
    int hh = 5;
    for (int i = 0; i < 5; ++i) if (col < starts[i + 1]) { hh = i; break; }
    int qc = astarts[hh] + (col - starts[hh]);
    cmap[col] = qc;
    cmap[512 + col] = QKSTRIDE + qc;
    cmap[1024 + col] = 4096 + col;
  }
  float dv = sumh - 512.0f;
  float floss = dv * dv;
  float rsum = 0.f;
  for (int i = 0; i < 6; ++i) rsum += fmaxf(8.0f - hdf[i], 0.0f);
  floss += rsum / 6.0f;
  float il = 0.f;
  for (int i = 0; i < 6; ++i) { float dd = hdf[i] - (float)hdi[i]; il += dd * dd; }
  il /= 6.0f;
  loss_out[0] = floss + 0.5f * il;
}

// ---------------- converters ----------------
__global__ void conv_bf16_kernel(const float* __restrict__ x, unsigned short* __restrict__ y, int n4) {
  int i = blockIdx.x * blockDim.x + threadIdx.x;
  if (i >= n4) return;
  float4 v = reinterpret_cast<const float4*>(x)[i];
  union { unsigned short u[4]; uint2 q; } o;
  o.u[0] = f2bf(v.x); o.u[1] = f2bf(v.y); o.u[2] = f2bf(v.z); o.u[3] = f2bf(v.w);
  reinterpret_cast<uint2*>(y)[i] = o.q;
}

// WT[n][k] = bf16(W[k][n]), K fixed = 512
__global__ void convWT_kernel(const float* __restrict__ W, unsigned short* __restrict__ WT, int N) {
  int idx = blockIdx.x * blockDim.x + threadIdx.x;
  if (idx >= N * 512) return;
  int k = idx & 511, n = idx >> 9;
  WT[idx] = f2bf(W[(size_t)k * N + n]);
}

// ---------------- GEMM: C[M][N] = A[M][K](bf16) @ Bt[N][K]^T + bias ----------------
// MODE 0: f32 out to Cf. MODE 1: bf16 scatter via cmap to qkpad/vbuf.
template<int MODE>
__global__ __launch_bounds__(256, 2) void gemm_bt(
    const unsigned short* __restrict__ A,
    const unsigned short* __restrict__ Bt,
    const float* __restrict__ bias,
    float* __restrict__ Cf,
    unsigned short* __restrict__ qkpad,
    unsigned short* __restrict__ vbuf,
    const int* __restrict__ cmap,
    int N, int K)
{
  __shared__ unsigned short As[128 * 32];
  __shared__ unsigned short Bs[128 * 32];
  const int tid = threadIdx.x;
  const int wave = tid >> 6, lane = tid & 63;
  const int lrow = lane & 15, lgrp = lane >> 4;
  const int wm = wave >> 1, wn = wave & 1;
  const int brow = blockIdx.y * 128;
  const int bcol = blockIdx.x * 128;

  f32x4 acc[4][4];
#pragma unroll
  for (int m = 0; m < 4; ++m)
#pragma unroll
    for (int n = 0; n < 4; ++n) acc[m][n] = (f32x4){0.f, 0.f, 0.f, 0.f};

  const int sig0 = wave * 128 + lane;
  for (int kb = 0; kb < K; kb += 32) {
    __syncthreads();
#pragma unroll
    for (int it = 0; it < 2; ++it) {
      const int sigma = sig0 + it * 64;
      const int r = sigma >> 2, sp = sigma & 3;
      const int sl = sp ^ ((r >> 1) & 3);
      gload_lds16(&A[(size_t)(brow + r) * K + kb + sl * 8], &As[sigma * 8]);
    }
#pragma unroll
    for (int it = 0; it < 2; ++it) {
      const int sigma = sig0 + it * 64;
      const int r = sigma >> 2, sp = sigma & 3;
      const int sl = sp ^ ((r >> 1) & 3);
      gload_lds16(&Bt[(size_t)(bcol + r) * K + kb + sl * 8], &Bs[sigma * 8]);
    }
    __syncthreads();
    const int sub = (lgrp ^ ((lrow >> 1) & 3)) * 8;
    bf16x8 aF[4], bF[4];
#pragma unroll
    for (int m = 0; m < 4; ++m)
      aF[m] = *reinterpret_cast<const bf16x8*>(&As[(wm * 64 + m * 16 + lrow) * 32 + sub]);
#pragma unroll
    for (int n = 0; n < 4; ++n)
      bF[n] = *reinterpret_cast<const bf16x8*>(&Bs[(wn * 64 + n * 16 + lrow) * 32 + sub]);
#pragma unroll
    for (int m = 0; m < 4; ++m)
#pragma unroll
      for (int n = 0; n < 4; ++n)
        acc[m][n] = __builtin_amdgcn_mfma_f32_16x16x32_bf16(aF[m], bF[n], acc[m][n], 0, 0, 0);
  }

#pragma unroll
  for (int n = 0; n < 4; ++n) {
    const int col = bcol + wn * 64 + n * 16 + lrow;
    const float bv = bias[col];
    int mc = 0;
    if (MODE == 1) mc = cmap[col];
#pragma unroll
    for (int m = 0; m < 4; ++m) {
#pragma unroll
      for (int r = 0; r < 4; ++r) {
        const int row = brow + wm * 64 + m * 16 + lgrp * 4 + r;
        const float v = acc[m][n][r] + bv;
        if (MODE == 0) {
          Cf[(size_t)row * N + col] = v;
        } else {
          if (mc < 4096) qkpad[(size_t)row * QKROW + mc] = f2bf(v);
          else vbuf[(size_t)row * 512 + (mc - 4096)] = f2bf(v);
        }
      }
    }
  }
}

// ---------------- V transpose: Vt[b][c][t] = vbuf[(b*2048+t)*512 + c] ----------------
__global__ void transV_kernel(const unsigned short* __restrict__ vbuf, unsigned short* __restrict__ Vt) {
  __shared__ unsigned short tile[64][33];
  const int b = blockIdx.z, c0 = blockIdx.y * 32, t0 = blockIdx.x * 64;
  const int i = threadIdx.x;
  {
    int r = i >> 2, cc = (i & 3) * 8;
    u16x8 v = *reinterpret_cast<const u16x8*>(&vbuf[(size_t)(b * 2048 + t0 + r) * 512 + c0 + cc]);
#pragma unroll
    for (int j = 0; j < 8; ++j) tile[r][cc + j] = v[j];
  }
  __syncthreads();
  {
    int c = i >> 3, tt = (i & 7) * 8;
    u16x8 v;
#pragma unroll
    for (int j = 0; j < 8; ++j) v[j] = tile[tt + j][c];
    *reinterpret_cast<u16x8*>(&Vt[(size_t)(b * VTPAD + c0 + c) * 2048 + t0 + tt]) = v;
  }
}

// ---------------- flash attention, 4 independent waves, 16 q-rows/wave ----------------
template<int NCLO, int NCHI>
__global__ __launch_bounds__(256, 2) void attn_kernel(
    const unsigned short* __restrict__ qkpad,
    const unsigned short* __restrict__ Vt,
    unsigned short* __restrict__ attnC,
    const int* __restrict__ hdr)
{
  const int h = blockIdx.y, b = blockIdx.z;
  const int d = hdr[h];
  const int nc = (d + 31) >> 5;
  if (nc <= NCLO || nc > NCHI) return;
  const int start = hdr[8 + h];
  const int astart = hdr[16 + h];
  const int wave = threadIdx.x >> 6;
  const int lane = threadIdx.x & 63;
  const int lrow = lane & 15, lgrp = lane >> 4;
  const int q0 = blockIdx.x * 64 + wave * 16;
  const int ntiles = (d + 15) >> 4;
  const float scale = 1.0f / sqrtf((float)d);

  __shared__ unsigned short Pl[2][4][16 * 32];

  bf16x8 qf[NCHI];
  {
    const size_t qbase = (size_t)(b * 2048 + q0 + lrow) * QKROW + astart;
#pragma unroll
    for (int dc = 0; dc < NCHI; ++dc) {
      if (dc < nc) {
        bf16x8 v = *reinterpret_cast<const bf16x8*>(&qkpad[qbase + dc * 32 + lgrp * 8]);
#pragma unroll
        for (int j = 0; j < 8; ++j)
          if (dc * 32 + lgrp * 8 + j >= d) v[j] = (__bf16)0.0f;
        qf[dc] = v;
      }
    }
  }

  f32x4 acc[2 * NCHI];
#pragma unroll
  for (int t = 0; t < 2 * NCHI; ++t) acc[t] = (f32x4){0.f, 0.f, 0.f, 0.f};
  float m_run[4] = {-1e30f, -1e30f, -1e30f, -1e30f};
  float l_run[4] = {0.f, 0.f, 0.f, 0.f};

  for (int kt = 0; kt < 2048; kt += 32) {
    f32x4 s0 = {0.f, 0.f, 0.f, 0.f}, s1 = {0.f, 0.f, 0.f, 0.f};
    const size_t kb0 = (size_t)(b * 2048 + kt + lrow) * QKROW + QKSTRIDE + astart;
    const size_t kb1 = kb0 + (size_t)16 * QKROW;
#pragma unroll
    for (int dc = 0; dc < NCHI; ++dc) {
      if (dc < nc) {
        bf16x8 k0 = *reinterpret_cast<const bf16x8*>(&qkpad[kb0 + dc * 32 + lgrp * 8]);
        bf16x8 k1 = *reinterpret_cast<const bf16x8*>(&qkpad[kb1 + dc * 32 + lgrp * 8]);
        s0 = __builtin_amdgcn_mfma_f32_16x16x32_bf16(qf[dc], k0, s0, 0, 0, 0);
        s1 = __builtin_amdgcn_mfma_f32_16x16x32_bf16(qf[dc], k1, s1, 0, 0, 0);
      }
    }
    float p0[4], p1[4], pmax[4];
#pragma unroll
    for (int r = 0; r < 4; ++r) {
      p0[r] = s0[r] * scale; p1[r] = s1[r] * scale;
      float mx = fmaxf(p0[r], p1[r]);
#pragma unroll
      for (int off = 1; off < 16; off <<= 1) mx = fmaxf(mx, __shfl_xor(mx, off));
      pmax[r] = mx;
    }
    bool need = false;
#pragma unroll
    for (int r = 0; r < 4; ++r) need = need || (pmax[r] > m_run[r] + 8.0f);
    if (__any(need)) {
#pragma unroll
      for (int r = 0; r < 4; ++r) {
        float mn = fmaxf(m_run[r], pmax[r]);
        float al = __expf(m_run[r] - mn);
        m_run[r] = mn; l_run[r] *= al;
#pragma unroll
        for (int t = 0; t < 2 * NCHI; ++t)
          if (t < ntiles) acc[t][r] *= al;
      }
    }
#pragma unroll
    for (int r = 0; r < 4; ++r) {
      p0[r] = __expf(p0[r] - m_run[r]);
      p1[r] = __expf(p1[r] - m_run[r]);
      float sm = p0[r] + p1[r];
#pragma unroll
      for (int off = 1; off < 16; off <<= 1) sm += __shfl_xor(sm, off);
      l_run[r] += sm;
    }
    const int pb = (kt >> 5) & 1;
    unsigned short* P = &Pl[pb][wave][0];
#pragma unroll
    for (int r = 0; r < 4; ++r) {
      P[(lgrp * 4 + r) * 32 + lrow] = f2bf(p0[r]);
      P[(lgrp * 4 + r) * 32 + 16 + lrow] = f2bf(p1[r]);
    }
    asm volatile("s_waitcnt lgkmcnt(0)" ::: "memory");
    bf16x8 pf = *reinterpret_cast<const bf16x8*>(&P[lrow * 32 + lgrp * 8]);
    const size_t vbase = (size_t)(b * VTPAD + start) * 2048 + kt + lgrp * 8;
#pragma unroll
    for (int t = 0; t < 2 * NCHI; ++t) {
      if (t < ntiles) {
        bf16x8 vf = *reinterpret_cast<const bf16x8*>(&Vt[vbase + (size_t)(t * 16 + lrow) * 2048]);
        acc[t] = __builtin_amdgcn_mfma_f32_16x16x32_bf16(pf, vf, acc[t], 0, 0, 0);
      }
    }
  }

  float inv[4];
#pragma unroll
  for (int r = 0; r < 4; ++r) inv[r] = 1.0f / l_run[r];
#pragma unroll
  for (int t = 0; t < 2 * NCHI; ++t) {
    if (t < ntiles) {
      int col = t * 16 + lrow;
      if (col < d) {
#pragma unroll
        for (int r = 0; r < 4; ++r) {
          attnC[(size_t)(b * 2048 + q0 + lgrp * 4 + r) * 512 + start + col] =
              f2bf(acc[t][r] * inv[r]);
        }
      }
    }
  }
}

// ---------------- launch ----------------
extern "C" void kernel_launch(void* const* d_in, const int* in_sizes, int n_in,
                              void* d_out, int out_size, void* d_ws, size_t ws_size,
                              hipStream_t stream) {
  const float* query  = (const float*)d_in[0];
  const float* logits = (const float*)d_in[1];
  const float* w_qkv  = (const float*)d_in[2];
  const float* b_qkv  = (const float*)d_in[3];
  const float* w_out  = (const float*)d_in[4];
  const float* b_out  = (const float*)d_in[5];
  float* out = (float*)d_out;

  char* p = (char*)d_ws;
  size_t off = 0;
  auto alloc = [&](size_t bytes) {
    void* r = p + off; off += (bytes + 255) & ~(size_t)255; return r;
  };
  int* hdr              = (int*)alloc(1024);
  int* cmap             = (int*)alloc(1536 * 4);
  unsigned short* qbf   = (unsigned short*)alloc((size_t)8192 * 512 * 2);
  unsigned short* wqkvT = (unsigned short*)alloc((size_t)1536 * 512 * 2);
  unsigned short* woutT = (unsigned short*)alloc((size_t)512 * 512 * 2);
  unsigned short* qkpad = (unsigned short*)alloc((size_t)8192 * QKROW * 2);
  unsigned short* vbuf  = (unsigned short*)alloc((size_t)8192 * 512 * 2);
  unsigned short* Vt    = (unsigned short*)alloc((size_t)4 * VTPAD * 2048 * 2);
  unsigned short* attnC = (unsigned short*)alloc((size_t)8192 * 512 * 2);
  (void)ws_size; (void)in_sizes; (void)n_in; (void)out_size;

  prep_kernel<<<1, 64, 0, stream>>>(logits, hdr, cmap, out + 4194304);
  conv_bf16_kernel<<<4096, 256, 0, stream>>>(query, qbf, 8192 * 512 / 4);
  convWT_kernel<<<3072, 256, 0, stream>>>(w_qkv, wqkvT, 1536);
  convWT_kernel<<<1024, 256, 0, stream>>>(w_out, woutT, 512);
  gemm_bt<1><<<dim3(12, 64), 256, 0, stream>>>(qbf, wqkvT, b_qkv, nullptr, qkpad, vbuf, cmap, 1536, 512);
  transV_kernel<<<dim3(32, 16, 4), 256, 0, stream>>>(vbuf, Vt);
  dim3 ag(32, 6, 4);
  attn_kernel<0, 4><<<ag, 256, 0, stream>>>(qkpad, Vt, attnC, hdr);
  attn_kernel<4, 8><<<ag, 256, 0, stream>>>(qkpad, Vt, attnC, hdr);
  attn_kernel<8, 15><<<ag, 256, 0, stream>>>(qkpad, Vt, attnC, hdr);
  gemm_bt<0><<<dim3(4, 64), 256, 0, stream>>>(attnC, woutT, b_out, out, nullptr, nullptr, nullptr, 512, 512);
}

// Round 2
// 401.210 us; speedup vs baseline: 1.9410x; 1.9410x over previous
//
#include <hip/hip_runtime.h>
#include <hip/hip_bf16.h>
#include <cstdint>

typedef __attribute__((ext_vector_type(8))) __bf16 bf16x8;
typedef __attribute__((ext_vector_type(8))) unsigned short u16x8;
typedef __attribute__((ext_vector_type(4))) float f32x4;

#define QKSTRIDE 640
#define QKROW 1280
#define VTPAD 528

static __device__ __forceinline__ unsigned short f2bf(float f) {
  __hip_bfloat16 h = __float2bfloat16(f);
  return *reinterpret_cast<unsigned short*>(&h);
}

static __device__ __forceinline__ void gload_lds16(const void* g, void* lds) {
  __builtin_amdgcn_global_load_lds(
      (const __attribute__((address_space(1))) unsigned int*)g,
      (__attribute__((address_space(3))) unsigned int*)lds, 16, 0, 0);
}

// ---------------- prep: head dims, loss, column map ----------------
__global__ void prep_kernel(const float* __restrict__ logits, int* __restrict__ hdr,
                            int* __restrict__ cmap, float* __restrict__ loss_out) {
  if (threadIdx.x != 0 || blockIdx.x != 0) return;
  float l[6]; float mx = -1e30f;
  for (int i = 0; i < 6; ++i) { l[i] = logits[i]; mx = fmaxf(mx, l[i]); }
  float e[6]; float s = 0.f;
  for (int i = 0; i < 6; ++i) { e[i] = expf(l[i] - mx); s += e[i]; }
  float hdf[6]; float sumh = 0.f;
  for (int i = 0; i < 6; ++i) { hdf[i] = 8.0f + (e[i] / s) * 464.0f; sumh += hdf[i]; }
  int hdi[6]; float res[6]; int isum = 0;
  for (int i = 0; i < 6; ++i) {
    float fl = floorf(hdf[i]);
    hdi[i] = (int)fl; res[i] = hdf[i] - fl; isum += hdi[i];
  }
  int diff = 512 - isum;
  bool used[6] = {false, false, false, false, false, false};
  if (diff > 0) {
    for (int t = 0; t < diff; ++t) {
      int best = -1; float bv = -1e30f;
      for (int i = 0; i < 6; ++i) if (!used[i] && res[i] > bv) { bv = res[i]; best = i; }
      used[best] = true; hdi[best] += 1;
    }
  } else if (diff < 0) {
    for (int t = 0; t < -diff; ++t) {
      int best = -1; float bv = 1e30f;
      for (int i = 0; i < 6; ++i) if (!used[i] && res[i] < bv) { bv = res[i]; best = i; }
      used[best] = true; hdi[best] -= 1;
    }
  }
  int starts[6], astarts[6];
  { int st = 0, ast = 0;
    for (int i = 0; i < 6; ++i) {
      starts[i] = st; astarts[i] = ast;
      hdr[i] = hdi[i]; hdr[8 + i] = st; hdr[16 + i] = ast;
      st += hdi[i]; ast += (hdi[i] + 7) & ~7;
    } }
  for (int col = 0; col < 512; ++col) {
    int hh = 5;
    for (int i = 0; i < 5; ++i) if (col < starts[i + 1]) { hh = i; break; }
    int qc = astarts[hh] + (col - starts[hh]);
    cmap[col] = qc;
    cmap[512 + col] = QKSTRIDE + qc;
    cmap[1024 + col] = 4096 + col;
  }
  float dv = sumh - 512.0f;
  float floss = dv * dv;
  float rsum = 0.f;
  for (int i = 0; i < 6; ++i) rsum += fmaxf(8.0f - hdf[i], 0.0f);
  floss += rsum / 6.0f;
  float il = 0.f;
  for (int i = 0; i < 6; ++i) { float dd = hdf[i] - (float)hdi[i]; il += dd * dd; }
  il /= 6.0f;
  loss_out[0] = floss + 0.5f * il;
}

// ---------------- converters ----------------
__global__ void conv_bf16_kernel(const float* __restrict__ x, unsigned short* __restrict__ y, int n4) {
  int i = blockIdx.x * blockDim.x + threadIdx.x;
  if (i >= n4) return;
  float4 v = reinterpret_cast<const float4*>(x)[i];
  union { unsigned short u[4]; uint2 q; } o;
  o.u[0] = f2bf(v.x); o.u[1] = f2bf(v.y); o.u[2] = f2bf(v.z); o.u[3] = f2bf(v.w);
  reinterpret_cast<uint2*>(y)[i] = o.q;
}

// WT[n][k] = bf16(W[k][n]), K fixed = 512
__global__ void convWT_kernel(const float* __restrict__ W, unsigned short* __restrict__ WT, int N) {
  int idx = blockIdx.x * blockDim.x + threadIdx.x;
  if (idx >= N * 512) return;
  int k = idx & 511, n = idx >> 9;
  WT[idx] = f2bf(W[(size_t)k * N + n]);
}

// ---------------- GEMM: C[M][N] = A[M][K](bf16) @ Bt[N][K]^T + bias ----------------
template<int MODE>
__global__ __launch_bounds__(256, 2) void gemm_bt(
    const unsigned short* __restrict__ A,
    const unsigned short* __restrict__ Bt,
    const float* __restrict__ bias,
    float* __restrict__ Cf,
    unsigned short* __restrict__ qkpad,
    unsigned short* __restrict__ vbuf,
    const int* __restrict__ cmap,
    int N, int K)
{
  __shared__ unsigned short As[128 * 32];
  __shared__ unsigned short Bs[128 * 32];
  const int tid = threadIdx.x;
  const int wave = tid >> 6, lane = tid & 63;
  const int lrow = lane & 15, lgrp = lane >> 4;
  const int wm = wave >> 1, wn = wave & 1;
  const int brow = blockIdx.y * 128;
  const int bcol = blockIdx.x * 128;

  f32x4 acc[4][4];
#pragma unroll
  for (int m = 0; m < 4; ++m)
#pragma unroll
    for (int n = 0; n < 4; ++n) acc[m][n] = (f32x4){0.f, 0.f, 0.f, 0.f};

  const int sig0 = wave * 128 + lane;
  for (int kb = 0; kb < K; kb += 32) {
    __syncthreads();
#pragma unroll
    for (int it = 0; it < 2; ++it) {
      const int sigma = sig0 + it * 64;
      const int r = sigma >> 2, sp = sigma & 3;
      const int sl = sp ^ ((r >> 1) & 3);
      gload_lds16(&A[(size_t)(brow + r) * K + kb + sl * 8], &As[sigma * 8]);
    }
#pragma unroll
    for (int it = 0; it < 2; ++it) {
      const int sigma = sig0 + it * 64;
      const int r = sigma >> 2, sp = sigma & 3;
      const int sl = sp ^ ((r >> 1) & 3);
      gload_lds16(&Bt[(size_t)(bcol + r) * K + kb + sl * 8], &Bs[sigma * 8]);
    }
    __syncthreads();
    const int sub = (lgrp ^ ((lrow >> 1) & 3)) * 8;
    bf16x8 aF[4], bF[4];
#pragma unroll
    for (int m = 0; m < 4; ++m)
      aF[m] = *reinterpret_cast<const bf16x8*>(&As[(wm * 64 + m * 16 + lrow) * 32 + sub]);
#pragma unroll
    for (int n = 0; n < 4; ++n)
      bF[n] = *reinterpret_cast<const bf16x8*>(&Bs[(wn * 64 + n * 16 + lrow) * 32 + sub]);
#pragma unroll
    for (int m = 0; m < 4; ++m)
#pragma unroll
      for (int n = 0; n < 4; ++n)
        acc[m][n] = __builtin_amdgcn_mfma_f32_16x16x32_bf16(aF[m], bF[n], acc[m][n], 0, 0, 0);
  }

#pragma unroll
  for (int n = 0; n < 4; ++n) {
    const int col = bcol + wn * 64 + n * 16 + lrow;
    const float bv = bias[col];
    int mc = 0;
    if (MODE == 1) mc = cmap[col];
#pragma unroll
    for (int m = 0; m < 4; ++m) {
#pragma unroll
      for (int r = 0; r < 4; ++r) {
        const int row = brow + wm * 64 + m * 16 + lgrp * 4 + r;
        const float v = acc[m][n][r] + bv;
        if (MODE == 0) {
          Cf[(size_t)row * N + col] = v;
        } else {
          if (mc < 4096) qkpad[(size_t)row * QKROW + mc] = f2bf(v);
          else vbuf[(size_t)row * 512 + (mc - 4096)] = f2bf(v);
        }
      }
    }
  }
}

// ---------------- V transpose ----------------
__global__ void transV_kernel(const unsigned short* __restrict__ vbuf, unsigned short* __restrict__ Vt) {
  __shared__ unsigned short tile[64][33];
  const int b = blockIdx.z, c0 = blockIdx.y * 32, t0 = blockIdx.x * 64;
  const int i = threadIdx.x;
  {
    int r = i >> 2, cc = (i & 3) * 8;
    u16x8 v = *reinterpret_cast<const u16x8*>(&vbuf[(size_t)(b * 2048 + t0 + r) * 512 + c0 + cc]);
#pragma unroll
    for (int j = 0; j < 8; ++j) tile[r][cc + j] = v[j];
  }
  __syncthreads();
  {
    int c = i >> 3, tt = (i & 7) * 8;
    u16x8 v;
#pragma unroll
    for (int j = 0; j < 8; ++j) v[j] = tile[tt + j][c];
    *reinterpret_cast<u16x8*>(&Vt[(size_t)(b * VTPAD + c0 + c) * 2048 + t0 + tt]) = v;
  }
}

// ---------------- staged flash attention (all heads with nc<=8) ----------------
// 2-phase pipeline: stage(next tile) -> compute(cur) -> __syncthreads().
// K LDS: runtime row width S slots (S=ceil8(4*nc)), XOR-swizzle slot^(r&7),
// applied on the pre-swizzled GLOBAL source (involution; rule #21).
// V LDS: 64B rows, swizzle slot^((rv>>1)&3) -> 2-way (free).
__global__ __launch_bounds__(256, 2) void attn_staged(
    const unsigned short* __restrict__ qkpad,
    const unsigned short* __restrict__ Vt,
    unsigned short* __restrict__ attnC,
    const int* __restrict__ hdr)
{
  const int h = blockIdx.y, b = blockIdx.z;
  const int d = hdr[h];
  const int nc = (d + 31) >> 5;
  if (nc > 8) return;
  const int start = hdr[8 + h];
  const int astart = hdr[16 + h];
  const int tid = threadIdx.x;
  const int wave = tid >> 6, lane = tid & 63;
  const int lrow = lane & 15, lgrp = lane >> 4;
  const int q0 = blockIdx.x * 64 + wave * 16;
  const int ntiles = (d + 15) >> 4;
  const float scale = 1.0f / sqrtf((float)d);

  const int S = (4 * nc + 7) & ~7;        // K slots per row (16B units)
  const int kInstr = S >> 1;              // wave-instructions to stage K tile (32 rows)
  const float invS = 1.0f / (float)S;
  const int rowBytesK = S * 16;

  __shared__ unsigned short Ks[2][32 * 256];   // 16KB each (max S=32)
  __shared__ unsigned short Vs[2][256 * 32];   // 16KB each (max 256 rows x 64B)
  __shared__ unsigned short Pl[4][16 * 32];

  // ---- Q fragments (held for the whole kernel) ----
  bf16x8 qf[8];
  {
    const size_t qbase = (size_t)(b * 2048 + q0 + lrow) * QKROW + astart;
#pragma unroll
    for (int dc = 0; dc < 8; ++dc) {
      if (dc < nc) {
        bf16x8 v = *reinterpret_cast<const bf16x8*>(&qkpad[qbase + dc * 32 + lgrp * 8]);
#pragma unroll
        for (int j = 0; j < 8; ++j)
          if (dc * 32 + lgrp * 8 + j >= d) v[j] = (__bf16)0.0f;
        qf[dc] = v;
      }
    }
  }

  const char* kSrcBase = (const char*)qkpad + (size_t)(QKSTRIDE + astart) * 2;
  const char* vSrcBase = (const char*)Vt;

  auto stage = [&](int buf, int kt) {
    // K tile: rows kt..kt+31, S slots per row, linear-packed LDS (stride rowBytesK)
    char* kDst = (char*)&Ks[buf][0];
#pragma unroll
    for (int j = 0; j < 4; ++j) {
      const int ki = wave + 4 * j;
      if (ki < kInstr) {
        const int g = ki * 64 + lane;                // linear 16B-slot index
        const int r = (int)(((float)g + 0.5f) * invS);
        const int p = g - r * S;
        const int sp = p ^ (r & 7);
        const char* src = kSrcBase + (size_t)(b * 2048 + kt + r) * (QKROW * 2) + sp * 16;
        gload_lds16(src, kDst + g * 16);
      }
    }
    // V tile: rows start..start+ntiles*16-1 (head cols), 32 time cols (64B)
    char* vDst = (char*)&Vs[buf][0];
#pragma unroll
    for (int j = 0; j < 4; ++j) {
      const int vi = wave + 4 * j;
      if (vi < ntiles) {
        const int rv = vi * 16 + (lane >> 2);
        const int p = lane & 3;
        const int sp = p ^ ((rv >> 1) & 3);
        const char* src = vSrcBase + ((size_t)(b * VTPAD + start + rv) * 2048 + kt) * 2 + sp * 16;
        gload_lds16(src, vDst + vi * 1024 + lane * 16);
      }
    }
  };

  f32x4 acc[16];
#pragma unroll
  for (int t = 0; t < 16; ++t) acc[t] = (f32x4){0.f, 0.f, 0.f, 0.f};
  float m_run[4] = {-1e30f, -1e30f, -1e30f, -1e30f};
  float l_run[4] = {0.f, 0.f, 0.f, 0.f};

  stage(0, 0);
  __syncthreads();

  for (int kt = 0; kt < 2048; kt += 32) {
    const int cur = (kt >> 5) & 1;
    if (kt + 32 < 2048) stage(cur ^ 1, kt + 32);

    // ---- QK^T from LDS ----
    f32x4 s0 = {0.f, 0.f, 0.f, 0.f}, s1 = {0.f, 0.f, 0.f, 0.f};
    const char* kBase = (const char*)&Ks[cur][0];
    const int swz = lrow & 7;
#pragma unroll
    for (int dc = 0; dc < 8; ++dc) {
      if (dc < nc) {
        const int phys = (dc * 4 + lgrp) ^ swz;
        bf16x8 k0 = *reinterpret_cast<const bf16x8*>(kBase + lrow * rowBytesK + phys * 16);
        bf16x8 k1 = *reinterpret_cast<const bf16x8*>(kBase + (lrow + 16) * rowBytesK + phys * 16);
        s0 = __builtin_amdgcn_mfma_f32_16x16x32_bf16(qf[dc], k0, s0, 0, 0, 0);
        s1 = __builtin_amdgcn_mfma_f32_16x16x32_bf16(qf[dc], k1, s1, 0, 0, 0);
      }
    }

    // ---- online softmax (wave-parallel; defer-max THR=8) ----
    float p0[4], p1[4], pmax[4];
#pragma unroll
    for (int r = 0; r < 4; ++r) {
      p0[r] = s0[r] * scale; p1[r] = s1[r] * scale;
      float mx = fmaxf(p0[r], p1[r]);
#pragma unroll
      for (int off = 1; off < 16; off <<= 1) mx = fmaxf(mx, __shfl_xor(mx, off));
      pmax[r] = mx;
    }
    bool need = false;
#pragma unroll
    for (int r = 0; r < 4; ++r) need = need || (pmax[r] > m_run[r] + 8.0f);
    if (__any(need)) {
#pragma unroll
      for (int r = 0; r < 4; ++r) {
        float mn = fmaxf(m_run[r], pmax[r]);
        float al = __expf(m_run[r] - mn);
        m_run[r] = mn; l_run[r] *= al;
#pragma unroll
        for (int t = 0; t < 16; ++t)
          if (t < ntiles) acc[t][r] *= al;
      }
    }
#pragma unroll
    for (int r = 0; r < 4; ++r) {
      p0[r] = __expf(p0[r] - m_run[r]);
      p1[r] = __expf(p1[r] - m_run[r]);
      float sm = p0[r] + p1[r];
#pragma unroll
      for (int off = 1; off < 16; off <<= 1) sm += __shfl_xor(sm, off);
      l_run[r] += sm;
    }

    // ---- P -> LDS bounce into A-fragment layout ----
    unsigned short* P = &Pl[wave][0];
#pragma unroll
    for (int r = 0; r < 4; ++r) {
      P[(lgrp * 4 + r) * 32 + lrow] = f2bf(p0[r]);
      P[(lgrp * 4 + r) * 32 + 16 + lrow] = f2bf(p1[r]);
    }
    asm volatile("s_waitcnt lgkmcnt(0)" ::: "memory");
    bf16x8 pf = *reinterpret_cast<const bf16x8*>(&P[lrow * 32 + lgrp * 8]);

    // ---- PV from LDS ----
    const char* vBase = (const char*)&Vs[cur][0];
#pragma unroll
    for (int t = 0; t < 16; ++t) {
      if (t < ntiles) {
        const int rv = t * 16 + lrow;
        const int sp = lgrp ^ ((rv >> 1) & 3);
        bf16x8 vf = *reinterpret_cast<const bf16x8*>(vBase + rv * 64 + sp * 16);
        acc[t] = __builtin_amdgcn_mfma_f32_16x16x32_bf16(pf, vf, acc[t], 0, 0, 0);
      }
    }
    __syncthreads();
  }

  float inv[4];
#pragma unroll
  for (int r = 0; r < 4; ++r) inv[r] = 1.0f / l_run[r];
#pragma unroll
  for (int t = 0; t < 16; ++t) {
    if (t < ntiles) {
      int col = t * 16 + lrow;
      if (col < d) {
#pragma unroll
        for (int r = 0; r < 4; ++r) {
          attnC[(size_t)(b * 2048 + q0 + lgrp * 4 + r) * 512 + start + col] =
              f2bf(acc[t][r] * inv[r]);
        }
      }
    }
  }
}

// ---------------- direct fallback for nc>8 (d>256), usually all-exit ----------------
template<int NCLO, int NCHI>
__global__ __launch_bounds__(256, 2) void attn_kernel(
    const unsigned short* __restrict__ qkpad,
    const unsigned short* __restrict__ Vt,
    unsigned short* __restrict__ attnC,
    const int* __restrict__ hdr)
{
  const int h = blockIdx.y, b = blockIdx.z;
  const int d = hdr[h];
  const int nc = (d + 31) >> 5;
  if (nc <= NCLO || nc > NCHI) return;
  const int start = hdr[8 + h];
  const int astart = hdr[16 + h];
  const int wave = threadIdx.x >> 6;
  const int lane = threadIdx.x & 63;
  const int lrow = lane & 15, lgrp = lane >> 4;
  const int q0 = blockIdx.x * 64 + wave * 16;
  const int ntiles = (d + 15) >> 4;
  const float scale = 1.0f / sqrtf((float)d);

  __shared__ unsigned short Pl[2][4][16 * 32];

  bf16x8 qf[NCHI];
  {
    const size_t qbase = (size_t)(b * 2048 + q0 + lrow) * QKROW + astart;
#pragma unroll
    for (int dc = 0; dc < NCHI; ++dc) {
      if (dc < nc) {
        bf16x8 v = *reinterpret_cast<const bf16x8*>(&qkpad[qbase + dc * 32 + lgrp * 8]);
#pragma unroll
        for (int j = 0; j < 8; ++j)
          if (dc * 32 + lgrp * 8 + j >= d) v[j] = (__bf16)0.0f;
        qf[dc] = v;
      }
    }
  }

  f32x4 acc[2 * NCHI];
#pragma unroll
  for (int t = 0; t < 2 * NCHI; ++t) acc[t] = (f32x4){0.f, 0.f, 0.f, 0.f};
  float m_run[4] = {-1e30f, -1e30f, -1e30f, -1e30f};
  float l_run[4] = {0.f, 0.f, 0.f, 0.f};

  for (int kt = 0; kt < 2048; kt += 32) {
    f32x4 s0 = {0.f, 0.f, 0.f, 0.f}, s1 = {0.f, 0.f, 0.f, 0.f};
    const size_t kb0 = (size_t)(b * 2048 + kt + lrow) * QKROW + QKSTRIDE + astart;
    const size_t kb1 = kb0 + (size_t)16 * QKROW;
#pragma unroll
    for (int dc = 0; dc < NCHI; ++dc) {
      if (dc < nc) {
        bf16x8 k0 = *reinterpret_cast<const bf16x8*>(&qkpad[kb0 + dc * 32 + lgrp * 8]);
        bf16x8 k1 = *reinterpret_cast<const bf16x8*>(&qkpad[kb1 + dc * 32 + lgrp * 8]);
        s0 = __builtin_amdgcn_mfma_f32_16x16x32_bf16(qf[dc], k0, s0, 0, 0, 0);
        s1 = __builtin_amdgcn_mfma_f32_16x16x32_bf16(qf[dc], k1, s1, 0, 0, 0);
      }
    }
    float p0[4], p1[4], pmax[4];
#pragma unroll
    for (int r = 0; r < 4; ++r) {
      p0[r] = s0[r] * scale; p1[r] = s1[r] * scale;
      float mx = fmaxf(p0[r], p1[r]);
#pragma unroll
      for (int off = 1; off < 16; off <<= 1) mx = fmaxf(mx, __shfl_xor(mx, off));
      pmax[r] = mx;
    }
    bool need = false;
#pragma unroll
    for (int r = 0; r < 4; ++r) need = need || (pmax[r] > m_run[r] + 8.0f);
    if (__any(need)) {
#pragma unroll
      for (int r = 0; r < 4; ++r) {
        float mn = fmaxf(m_run[r], pmax[r]);
        float al = __expf(m_run[r] - mn);
        m_run[r] = mn; l_run[r] *= al;
#pragma unroll
        for (int t = 0; t < 2 * NCHI; ++t)
          if (t < ntiles) acc[t][r] *= al;
      }
    }
#pragma unroll
    for (int r = 0; r < 4; ++r) {
      p0[r] = __expf(p0[r] - m_run[r]);
      p1[r] = __expf(p1[r] - m_run[r]);
      float sm = p0[r] + p1[r];
#pragma unroll
      for (int off = 1; off < 16; off <<= 1) sm += __shfl_xor(sm, off);
      l_run[r] += sm;
    }
    const int pb = (kt >> 5) & 1;
    unsigned short* P = &Pl[pb][wave][0];
#pragma unroll
    for (int r = 0; r < 4; ++r) {
      P[(lgrp * 4 + r) * 32 + lrow] = f2bf(p0[r]);
      P[(lgrp * 4 + r) * 32 + 16 + lrow] = f2bf(p1[r]);
    }
    asm volatile("s_waitcnt lgkmcnt(0)" ::: "memory");
    bf16x8 pf = *reinterpret_cast<const bf16x8*>(&P[lrow * 32 + lgrp * 8]);
    const size_t vbase = (size_t)(b * VTPAD + start) * 2048 + kt + lgrp * 8;
#pragma unroll
    for (int t = 0; t < 2 * NCHI; ++t) {
      if (t < ntiles) {
        bf16x8 vf = *reinterpret_cast<const bf16x8*>(&Vt[vbase + (size_t)(t * 16 + lrow) * 2048]);
        acc[t] = __builtin_amdgcn_mfma_f32_16x16x32_bf16(pf, vf, acc[t], 0, 0, 0);
      }
    }
  }

  float inv[4];
#pragma unroll
  for (int r = 0; r < 4; ++r) inv[r] = 1.0f / l_run[r];
#pragma unroll
  for (int t = 0; t < 2 * NCHI; ++t) {
    if (t < ntiles) {
      int col = t * 16 + lrow;
      if (col < d) {
#pragma unroll
        for (int r = 0; r < 4; ++r) {
          attnC[(size_t)(b * 2048 + q0 + lgrp * 4 + r) * 512 + start + col] =
              f2bf(acc[t][r] * inv[r]);
        }
      }
    }
  }
}

// ---------------- launch ----------------
extern "C" void kernel_launch(void* const* d_in, const int* in_sizes, int n_in,
                              void* d_out, int out_size, void* d_ws, size_t ws_size,
                              hipStream_t stream) {
  const float* query  = (const float*)d_in[0];
  const float* logits = (const float*)d_in[1];
  const float* w_qkv  = (const float*)d_in[2];
  const float* b_qkv  = (const float*)d_in[3];
  const float* w_out  = (const float*)d_in[4];
  const float* b_out  = (const float*)d_in[5];
  float* out = (float*)d_out;

  char* p = (char*)d_ws;
  size_t off = 0;
  auto alloc = [&](size_t bytes) {
    void* r = p + off; off += (bytes + 255) & ~(size_t)255; return r;
  };
  int* hdr              = (int*)alloc(1024);
  int* cmap             = (int*)alloc(1536 * 4);
  unsigned short* qbf   = (unsigned short*)alloc((size_t)8192 * 512 * 2);
  unsigned short* wqkvT = (unsigned short*)alloc((size_t)1536 * 512 * 2);
  unsigned short* woutT = (unsigned short*)alloc((size_t)512 * 512 * 2);
  unsigned short* qkpad = (unsigned short*)alloc((size_t)8192 * QKROW * 2 + 4096);
  unsigned short* vbuf  = (unsigned short*)alloc((size_t)8192 * 512 * 2);
  unsigned short* Vt    = (unsigned short*)alloc((size_t)4 * VTPAD * 2048 * 2 + 4096);
  unsigned short* attnC = (unsigned short*)alloc((size_t)8192 * 512 * 2);
  (void)ws_size; (void)in_sizes; (void)n_in; (void)out_size;

  prep_kernel<<<1, 64, 0, stream>>>(logits, hdr, cmap, out + 4194304);
  conv_bf16_kernel<<<4096, 256, 0, stream>>>(query, qbf, 8192 * 512 / 4);
  convWT_kernel<<<3072, 256, 0, stream>>>(w_qkv, wqkvT, 1536);
  convWT_kernel<<<1024, 256, 0, stream>>>(w_out, woutT, 512);
  gemm_bt<1><<<dim3(12, 64), 256, 0, stream>>>(qbf, wqkvT, b_qkv, nullptr, qkpad, vbuf, cmap, 1536, 512);
  transV_kernel<<<dim3(32, 16, 4), 256, 0, stream>>>(vbuf, Vt);
  dim3 ag(32, 6, 4);
  attn_staged<<<ag, 256, 0, stream>>>(qkpad, Vt, attnC, hdr);
  attn_kernel<8, 15><<<ag, 256, 0, stream>>>(qkpad, Vt, attnC, hdr);
  gemm_bt<0><<<dim3(4, 64), 256, 0, stream>>>(attnC, woutT, b_out, out, nullptr, nullptr, nullptr, 512, 512);
}